// Round 4
// baseline (134.381 us; speedup 1.0000x reference)
//
#include <hip/hip_runtime.h>
#include <cmath>

// ---------------- problem constants (idx = 0) ----------------
#define S_    80
#define NBAT  16
#define NA_   3
#define NCH_  255          // NB * (NC + 5)
#define NC_   80
#define PLANE (S_ * S_)    // 6400
#define CELLS (NBAT * NA_ * PLANE)   // 307200
#define MAXENT (256 * 15)  // N * 5 offsets * 3 anchors upper bound
#define WPB   4            // waves per block (masked part)
#define MBLK  (MAXENT / WPB)            // 960 masked blocks
#define OBLK  ((CELLS / 4 + 255) / 256) // 300 obj blocks
#define TOTBLK (MBLK + OBLK)            // 1260
#define FLAGW (CELLS / 32)              // 9600 words

__device__ __forceinline__ float sp(float x) {   // softplus, stable
    return fmaxf(x, 0.f) + log1pf(__expf(-fabsf(x)));
}

__device__ __forceinline__ float ciou_f(float x1, float y1, float w1, float h1,
                                        float x2, float y2, float w2, float h2) {
    const float EPS = 1e-7f;
    float b1x1 = x1 - w1 * 0.5f, b1x2 = x1 + w1 * 0.5f;
    float b1y1 = y1 - h1 * 0.5f, b1y2 = y1 + h1 * 0.5f;
    float b2x1 = x2 - w2 * 0.5f, b2x2 = x2 + w2 * 0.5f;
    float b2y1 = y2 - h2 * 0.5f, b2y2 = y2 + h2 * 0.5f;
    float iw = fmaxf(fminf(b1x2, b2x2) - fmaxf(b1x1, b2x1), 0.f);
    float ih = fmaxf(fminf(b1y2, b2y2) - fmaxf(b1y1, b2y1), 0.f);
    float inter = iw * ih;
    float uni = w1 * h1 + w2 * h2 - inter + EPS;
    float iou = inter / uni;
    float cw = fmaxf(b1x2, b2x2) - fminf(b1x1, b2x1);
    float ch = fmaxf(b1y2, b2y2) - fminf(b1y1, b2y1);
    float c2 = cw * cw + ch * ch + EPS;
    float dx = b2x1 + b2x2 - b1x1 - b1x2;
    float dy = b2y1 + b2y2 - b1y1 - b1y2;
    float rho2 = (dx * dx + dy * dy) * 0.25f;
    float da = atanf(w2 / (h2 + EPS)) - atanf(w1 / (h1 + EPS));
    float v = 0.40528473456935109f * da * da;   // 4/pi^2
    float alpha = v / (v - iou + (1.f + EPS));
    return iou - (rho2 / c2 + v * alpha);
}

// ---- kernel 1: clear flags/count/done in-kernel, then build target list ----
// single block, 1024 threads; replaces the hipMemsetAsync node.
__global__ void k_prep(const float* __restrict__ tgt, int N,
                       unsigned* __restrict__ flags, int* __restrict__ count,
                       int* __restrict__ done,
                       int* __restrict__ lcell, int* __restrict__ lcls,
                       float4* __restrict__ lbox) {
    int tid = threadIdx.x;
    for (int i = tid; i < FLAGW; i += 1024) flags[i] = 0u;
    if (tid == 0) { *count = 0; *done = 0; }
    __syncthreads();

    int lane = tid & 63;
    int n = tid;
    bool active = (n < N);
    int b = 0, cls = 0, ib = 0, jb = 0;
    float bx = 0.f, by = 0.f, bw = 0.f, bh = 0.f;
    bool rm[3] = {false, false, false};
    bool pos[5] = {false, false, false, false, false};
    if (active) {
        b   = (int)tgt[n * 6 + 0];
        cls = (int)tgt[n * 6 + 1];
        bx = tgt[n * 6 + 2]; by = tgt[n * 6 + 3];
        bw = tgt[n * 6 + 4]; bh = tgt[n * 6 + 5];
        if (b < 0 || b >= NBAT) active = false;
    }
    if (active) {
        const float ax[3] = {12.f / 8.f, 19.f / 8.f, 40.f / 8.f};
        const float ay[3] = {16.f / 8.f, 36.f / 8.f, 28.f / 8.f};
        float whx = bw * S_, why = bh * S_;
#pragma unroll
        for (int a = 0; a < 3; ++a) {
            float rx = whx / ax[a]; rx = fmaxf(rx, 1.f / rx);
            float ry = why / ay[a]; ry = fmaxf(ry, 1.f / ry);
            rm[a] = fmaxf(rx, ry) < 4.0f;
        }
        float gx = bx * S_, gy = by * S_;
        ib = (int)floorf(gx); jb = (int)floorf(gy);
        float oi = gx - floorf(gx), oj = gy - floorf(gy);
        pos[0] = true;
        pos[1] = (oi < 0.5f) && (gx > 1.f);
        pos[2] = (oj < 0.5f) && (gy > 1.f);
        pos[3] = (oi > 0.5f) && ((S_ - gx) > 1.f);
        pos[4] = (oj > 0.5f) && ((S_ - gy) > 1.f);
    }
    const int di[5] = {0, -1, 0, 1, 0};
    const int dj[5] = {0, 0, -1, 0, 1};
#pragma unroll
    for (int k = 0; k < 5; ++k) {
#pragma unroll
        for (int a = 0; a < 3; ++a) {
            bool want = false;
            int cell = 0;
            if (active && pos[k] && rm[a]) {
                int ii = ib + di[k], jj = jb + dj[k];
                if (ii >= 0 && ii < S_ && jj >= 0 && jj < S_) {  // ref drops OOB
                    cell = ((b * NA_ + a) * S_ + jj) * S_ + ii;
                    unsigned m = 1u << (cell & 31);
                    unsigned old = atomicOr(&flags[cell >> 5], m);
                    want = !(old & m);
                }
            }
            unsigned long long mask = __ballot(want);
            if (mask) {
                int leader = __ffsll(mask) - 1;
                int prefix = __popcll(mask & ((1ull << lane) - 1ull));
                int base = 0;
                if (lane == leader) base = atomicAdd(count, __popcll(mask));
                base = __shfl(base, leader, 64);
                if (want) {
                    int e = base + prefix;
                    lcell[e] = cell;
                    lcls[e]  = cls;
                    lbox[e]  = make_float4(bx, by, bw, bh);
                }
            }
        }
    }
}

// ---- kernel 2: fused masked-loss + dense-obj + last-block final reduce ----
__global__ void __launch_bounds__(256)
k_work(const float* __restrict__ preds,
       const int* __restrict__ count,
       const int* __restrict__ lcell,
       const int* __restrict__ lcls,
       const float4* __restrict__ lbox,
       double* __restrict__ partials,
       int* __restrict__ done,
       float* __restrict__ out) {
    int bid = blockIdx.x;
    int lane = threadIdx.x & 63, wid = threadIdx.x >> 6;
    double o_p = 0.0, b_p = 0.0, c_p = 0.0;

    __shared__ double sm[WPB][3];

    if (bid < MBLK) {
        // -------- masked cells: one wave per cell --------
        int t = bid * WPB + wid;
        double obj_c = 0.0, box_t = 0.0, cls_s = 0.0;
        if (t < *count) {
            int cell = lcell[t];
            int x = cell % S_;
            int y = (cell / S_) % S_;
            int a = (cell / PLANE) % NA_;
            int b = cell / (PLANE * NA_);
            const float* base = preds + (size_t)(b * NCH_ + a * 85) * PLANE + y * S_ + x;
            float v0 = base[lane * PLANE];
            float v1 = (lane < 21) ? base[(64 + lane) * PLANE] : 0.f;
            int clsch = 5 + lcls[t];
            float cs = 0.f;
            if (lane >= 5) { cs += sp(v0); if (lane == clsch) cs -= v0; }
            if (lane < 21) { cs += sp(v1); if (64 + lane == clsch) cs -= v1; }
#pragma unroll
            for (int o = 32; o > 0; o >>= 1) cs += __shfl_xor(cs, o, 64);
            float p0 = __shfl(v0, 0, 64);
            float p1 = __shfl(v0, 1, 64);
            float p2 = __shfl(v0, 2, 64);
            float p3 = __shfl(v0, 3, 64);
            float po = __shfl(v0, 4, 64);

            const float anx[3]  = {12.f, 19.f, 40.f};
            const float any_[3] = {16.f, 36.f, 28.f};
            float sx = 1.f / (1.f + __expf(-p0));
            float sy = 1.f / (1.f + __expf(-p1));
            float px = (sx * 2.f - 0.5f + (float)x) * (1.0f / S_);
            float py = (sy * 2.f - 0.5f + (float)y) * (1.0f / S_);
            float pw = __expf(p2) * anx[a] * (1.0f / 640.f);
            float ph = __expf(p3) * any_[a] * (1.0f / 640.f);

            float4 tb = lbox[t];
            float iou = ciou_f(px, py, pw, ph, tb.x, tb.y, tb.z, tb.w);
            if (lane == 0) {
                box_t = (double)(1.f - iou);
                cls_s = (double)cs;
                obj_c = (double)(-fmaxf(iou, 0.f) * po);   // bce(x,t)=sp(x)-t*x
            }
        }
        if (lane == 0) { sm[wid][0] = obj_c; sm[wid][1] = box_t; sm[wid][2] = cls_s; }
        __syncthreads();
        if (threadIdx.x == 0) {
#pragma unroll
            for (int w = 0; w < WPB; ++w) {
                o_p += sm[w][0]; b_p += sm[w][1]; c_p += sm[w][2];
            }
        }
    } else {
        // -------- dense softplus(pobj) over 3 obj channels --------
        int tid4 = (bid - MBLK) * 256 + threadIdx.x;   // over CELLS/4
        float v = 0.f;
        if (tid4 < CELLS / 4) {
            int plane = tid4 / (PLANE / 4);   // 0..47 (= b*3 + a)
            int pos   = tid4 % (PLANE / 4);
            int a = plane % NA_, b = plane / NA_;
            const float4* p4 = (const float4*)preds;
            float4 q = p4[(size_t)(b * NCH_ + a * 85 + 4) * (PLANE / 4) + pos];
            v = sp(q.x) + sp(q.y) + sp(q.z) + sp(q.w);
        }
#pragma unroll
        for (int o = 32; o > 0; o >>= 1) v += __shfl_xor(v, o, 64);
        if (lane == 0) { sm[wid][0] = (double)v; sm[wid][1] = 0.0; sm[wid][2] = 0.0; }
        __syncthreads();
        if (threadIdx.x == 0) {
#pragma unroll
            for (int w = 0; w < WPB; ++w) o_p += sm[w][0];
        }
    }

    // -------- publish partial, ticket, last block reduces --------
    if (threadIdx.x == 0) {
        __hip_atomic_store(&partials[(size_t)bid * 3 + 0], o_p, __ATOMIC_RELAXED, __HIP_MEMORY_SCOPE_AGENT);
        __hip_atomic_store(&partials[(size_t)bid * 3 + 1], b_p, __ATOMIC_RELAXED, __HIP_MEMORY_SCOPE_AGENT);
        __hip_atomic_store(&partials[(size_t)bid * 3 + 2], c_p, __ATOMIC_RELAXED, __HIP_MEMORY_SCOPE_AGENT);
    }
    __threadfence();
    __shared__ int ticket;
    if (threadIdx.x == 0)
        ticket = __hip_atomic_fetch_add(done, 1, __ATOMIC_ACQ_REL, __HIP_MEMORY_SCOPE_AGENT);
    __syncthreads();
    if (ticket != TOTBLK - 1) return;

    // last block: deterministic final reduction
    __threadfence();
    __shared__ double so[256], sb[256], sc[256];
    int tid = threadIdx.x;
    double o = 0, b = 0, c = 0;
    for (int i = tid; i < TOTBLK; i += 256) {
        o += __hip_atomic_load(&partials[(size_t)i * 3 + 0], __ATOMIC_RELAXED, __HIP_MEMORY_SCOPE_AGENT);
        b += __hip_atomic_load(&partials[(size_t)i * 3 + 1], __ATOMIC_RELAXED, __HIP_MEMORY_SCOPE_AGENT);
        c += __hip_atomic_load(&partials[(size_t)i * 3 + 2], __ATOMIC_RELAXED, __HIP_MEMORY_SCOPE_AGENT);
    }
    so[tid] = o; sb[tid] = b; sc[tid] = c;
    __syncthreads();
    for (int s = 128; s > 0; s >>= 1) {
        if (tid < s) { so[tid] += so[tid + s]; sb[tid] += sb[tid + s]; sc[tid] += sc[tid + s]; }
        __syncthreads();
    }
    if (tid == 0) {
        double nobj  = (double)(*count);
        double denom = fmax(nobj, 1.0);
        double loss_obj = so[0] / (double)CELLS;
        double loss_box = sb[0] / denom;
        double loss_cls = sc[0] / (denom * (double)NC_);
        double loss = (0.7 * 4.0) * loss_obj + 0.3 * loss_cls + 0.05 * loss_box;
        out[0] = (float)(loss * (double)NBAT);
    }
}

extern "C" void kernel_launch(void* const* d_in, const int* in_sizes, int n_in,
                              void* d_out, int out_size, void* d_ws, size_t ws_size,
                              hipStream_t stream) {
    (void)n_in; (void)out_size; (void)ws_size;
    const float* preds = (const float*)d_in[0];
    const float* tgt   = (const float*)d_in[1];
    int N = in_sizes[1] / 6;

    char* ws = (char*)d_ws;
    int*      count = (int*)(ws + 0);
    int*      done  = (int*)(ws + 8);
    unsigned* flags = (unsigned*)(ws + 64);                 // FLAGW words
    int*      lcell = (int*)(ws + 38464);                   // MAXENT ints
    int*      lcls  = (int*)(ws + 38464 + MAXENT * 4);
    float4*   lbox  = (float4*)(ws + 38464 + MAXENT * 8);   // 16B aligned
    double*   partials = (double*)(ws + 130624);            // TOTBLK*3 doubles

    k_prep<<<1, 1024, 0, stream>>>(tgt, N, flags, count, done, lcell, lcls, lbox);
    k_work<<<TOTBLK, 256, 0, stream>>>(preds, count, lcell, lcls, lbox,
                                       partials, done, (float*)d_out);
}

// Round 5
// 24.280 us; speedup vs baseline: 5.5347x; 5.5347x over previous
//
#include <hip/hip_runtime.h>
#include <cmath>

// ---------------- problem constants (idx = 0) ----------------
#define S_    80
#define NBAT  16
#define NA_   3
#define NCH_  255          // NB * (NC + 5)
#define NC_   80
#define PLANE (S_ * S_)    // 6400
#define CELLS (NBAT * NA_ * PLANE)   // 307200
#define WPB   4            // waves per block (masked part)
#define OBLK  ((CELLS / 4) / 256)    // 300 obj blocks (exact: 76800/256)
#define FLAGW (CELLS / 32)           // 9600 words = 38400 B

__device__ __forceinline__ float sp(float x) {   // softplus, stable
    return fmaxf(x, 0.f) + log1pf(__expf(-fabsf(x)));
}

__device__ __forceinline__ float ciou_f(float x1, float y1, float w1, float h1,
                                        float x2, float y2, float w2, float h2) {
    const float EPS = 1e-7f;
    float b1x1 = x1 - w1 * 0.5f, b1x2 = x1 + w1 * 0.5f;
    float b1y1 = y1 - h1 * 0.5f, b1y2 = y1 + h1 * 0.5f;
    float b2x1 = x2 - w2 * 0.5f, b2x2 = x2 + w2 * 0.5f;
    float b2y1 = y2 - h2 * 0.5f, b2y2 = y2 + h2 * 0.5f;
    float iw = fmaxf(fminf(b1x2, b2x2) - fmaxf(b1x1, b2x1), 0.f);
    float ih = fmaxf(fminf(b1y2, b2y2) - fmaxf(b1y1, b2y1), 0.f);
    float inter = iw * ih;
    float uni = w1 * h1 + w2 * h2 - inter + EPS;
    float iou = inter / uni;
    float cw = fmaxf(b1x2, b2x2) - fminf(b1x1, b2x1);
    float ch = fmaxf(b1y2, b2y2) - fminf(b1y1, b2y1);
    float c2 = cw * cw + ch * ch + EPS;
    float dx = b2x1 + b2x2 - b1x1 - b1x2;
    float dy = b2y1 + b2y2 - b1y1 - b1y2;
    float rho2 = (dx * dx + dy * dy) * 0.25f;
    float da = atanf(w2 / (h2 + EPS)) - atanf(w1 / (h1 + EPS));
    float v = 0.40528473456935109f * da * da;   // 4/pi^2
    float alpha = v / (v - iou + (1.f + EPS));
    return iou - (rho2 / c2 + v * alpha);
}

// ---- fused kernel: per-entry claim+loss (no build pass) + dense obj sum ----
// Blocks [0, mblk): one WAVE per raw candidate entry e = n*15 + k*3 + a.
//   The wave validates the entry, claims the cell via device-scope atomicOr
//   (first writer wins = dedup), and if it wins computes box/cls/obj-corr.
// Blocks [mblk, mblk+OBLK): dense softplus(pobj) over the 3 obj channels.
// Each block writes its partial triple with plain stores; NO device fences
// (R3 lesson: 1260 per-block release fences cost ~100 us on 8-XCD gfx950).
__global__ void __launch_bounds__(256)
k_work(const float* __restrict__ preds,
       const float* __restrict__ tgt, int N, int mblk,
       unsigned* __restrict__ flags,
       double* __restrict__ partials) {
    int bid = blockIdx.x;
    int lane = threadIdx.x & 63, wid = threadIdx.x >> 6;
    double o_p = 0.0, b_p = 0.0, c_p = 0.0;
    __shared__ double sm[WPB][3];

    if (bid < mblk) {
        // -------- masked candidate entries: one wave per entry --------
        int e = bid * WPB + wid;
        double obj_c = 0.0, box_t = 0.0, cls_s = 0.0;
        bool win = false;
        int cell = 0, cls = 0;
        float bx = 0.f, by = 0.f, bw = 0.f, bh = 0.f;
        if (e < N * 15) {
            int n = e / 15, r = e % 15;
            int k = r / 3, a = r % 3;
            int b = (int)tgt[n * 6 + 0];
            cls    = (int)tgt[n * 6 + 1];
            bx = tgt[n * 6 + 2]; by = tgt[n * 6 + 3];
            bw = tgt[n * 6 + 4]; bh = tgt[n * 6 + 5];
            if (b >= 0 && b < NBAT) {
                const float ax[3] = {12.f / 8.f, 19.f / 8.f, 40.f / 8.f};
                const float ay[3] = {16.f / 8.f, 36.f / 8.f, 28.f / 8.f};
                float rx = bw * S_ / ax[a]; rx = fmaxf(rx, 1.f / rx);
                float ry = bh * S_ / ay[a]; ry = fmaxf(ry, 1.f / ry);
                bool rm = fmaxf(rx, ry) < 4.0f;
                float gx = bx * S_, gy = by * S_;
                int ib = (int)floorf(gx), jb = (int)floorf(gy);
                float oi = gx - floorf(gx), oj = gy - floorf(gy);
                bool pos;
                switch (k) {
                    case 0: pos = true; break;
                    case 1: pos = (oi < 0.5f) && (gx > 1.f); break;
                    case 2: pos = (oj < 0.5f) && (gy > 1.f); break;
                    case 3: pos = (oi > 0.5f) && ((S_ - gx) > 1.f); break;
                    default: pos = (oj > 0.5f) && ((S_ - gy) > 1.f); break;
                }
                const int di[5] = {0, -1, 0, 1, 0};
                const int dj[5] = {0, 0, -1, 0, 1};
                int ii = ib + di[k], jj = jb + dj[k];
                if (rm && pos && ii >= 0 && ii < S_ && jj >= 0 && jj < S_) {
                    cell = ((b * NA_ + a) * S_ + jj) * S_ + ii;
                    if (lane == 0) {
                        unsigned m = 1u << (cell & 31);
                        unsigned old = atomicOr(&flags[cell >> 5], m);
                        win = !(old & m);
                    }
                    win = (bool)__shfl((int)win, 0, 64);
                }
            }
        }
        if (win) {
            int x = cell % S_;
            int y = (cell / S_) % S_;
            int a = (cell / PLANE) % NA_;
            int b = cell / (PLANE * NA_);
            const float* base = preds + (size_t)(b * NCH_ + a * 85) * PLANE + y * S_ + x;
            float v0 = base[lane * PLANE];
            float v1 = (lane < 21) ? base[(64 + lane) * PLANE] : 0.f;
            int clsch = 5 + cls;
            float cs = 0.f;
            if (lane >= 5) { cs += sp(v0); if (lane == clsch) cs -= v0; }
            if (lane < 21) { cs += sp(v1); if (64 + lane == clsch) cs -= v1; }
#pragma unroll
            for (int o = 32; o > 0; o >>= 1) cs += __shfl_xor(cs, o, 64);
            float p0 = __shfl(v0, 0, 64);
            float p1 = __shfl(v0, 1, 64);
            float p2 = __shfl(v0, 2, 64);
            float p3 = __shfl(v0, 3, 64);
            float po = __shfl(v0, 4, 64);

            const float anx[3]  = {12.f, 19.f, 40.f};
            const float any_[3] = {16.f, 36.f, 28.f};
            float sx = 1.f / (1.f + __expf(-p0));
            float sy = 1.f / (1.f + __expf(-p1));
            float px = (sx * 2.f - 0.5f + (float)x) * (1.0f / S_);
            float py = (sy * 2.f - 0.5f + (float)y) * (1.0f / S_);
            float pw = __expf(p2) * anx[a] * (1.0f / 640.f);
            float ph = __expf(p3) * any_[a] * (1.0f / 640.f);

            float iou = ciou_f(px, py, pw, ph, bx, by, bw, bh);
            if (lane == 0) {
                box_t = (double)(1.f - iou);
                cls_s = (double)cs;
                obj_c = (double)(-fmaxf(iou, 0.f) * po);   // bce(x,t)=sp(x)-t*x
            }
        }
        if (lane == 0) { sm[wid][0] = obj_c; sm[wid][1] = box_t; sm[wid][2] = cls_s; }
        __syncthreads();
        if (threadIdx.x == 0) {
#pragma unroll
            for (int w = 0; w < WPB; ++w) {
                o_p += sm[w][0]; b_p += sm[w][1]; c_p += sm[w][2];
            }
        }
    } else {
        // -------- dense softplus(pobj) over 3 obj channels --------
        int tid4 = (bid - mblk) * 256 + threadIdx.x;   // over CELLS/4
        float v = 0.f;
        if (tid4 < CELLS / 4) {
            int plane = tid4 / (PLANE / 4);   // 0..47 (= b*3 + a)
            int pos   = tid4 % (PLANE / 4);
            int a = plane % NA_, b = plane / NA_;
            const float4* p4 = (const float4*)preds;
            float4 q = p4[(size_t)(b * NCH_ + a * 85 + 4) * (PLANE / 4) + pos];
            v = sp(q.x) + sp(q.y) + sp(q.z) + sp(q.w);
        }
#pragma unroll
        for (int o = 32; o > 0; o >>= 1) v += __shfl_xor(v, o, 64);
        if (lane == 0) { sm[wid][0] = (double)v; }
        __syncthreads();
        if (threadIdx.x == 0) {
#pragma unroll
            for (int w = 0; w < WPB; ++w) o_p += sm[w][0];
        }
    }

    if (threadIdx.x == 0) {
        double* p = partials + (size_t)bid * 3;
        p[0] = o_p; p[1] = b_p; p[2] = c_p;   // plain stores; next kernel sees them
    }
}

// ---- final: popcount flags (= nobj) + reduce partials + scalar -------------
__global__ void k_final(const double* __restrict__ partials, int totblk,
                        const unsigned* __restrict__ flags,
                        float* __restrict__ out) {
    __shared__ double so[256], sb[256], sc[256];
    __shared__ int scnt[256];
    int tid = threadIdx.x;
    double o = 0, b = 0, c = 0;
    int cnt = 0;
    for (int i = tid; i < totblk; i += 256) {
        o += partials[(size_t)i * 3];
        b += partials[(size_t)i * 3 + 1];
        c += partials[(size_t)i * 3 + 2];
    }
    for (int i = tid; i < FLAGW; i += 256) cnt += __popc(flags[i]);
    so[tid] = o; sb[tid] = b; sc[tid] = c; scnt[tid] = cnt;
    __syncthreads();
    for (int s = 128; s > 0; s >>= 1) {
        if (tid < s) {
            so[tid] += so[tid + s]; sb[tid] += sb[tid + s];
            sc[tid] += sc[tid + s]; scnt[tid] += scnt[tid + s];
        }
        __syncthreads();
    }
    if (tid == 0) {
        double nobj  = (double)scnt[0];
        double denom = fmax(nobj, 1.0);
        double loss_obj = so[0] / (double)CELLS;
        double loss_box = sb[0] / denom;
        double loss_cls = sc[0] / (denom * (double)NC_);
        double loss = (0.7 * 4.0) * loss_obj + 0.3 * loss_cls + 0.05 * loss_box;
        out[0] = (float)(loss * (double)NBAT);
    }
}

extern "C" void kernel_launch(void* const* d_in, const int* in_sizes, int n_in,
                              void* d_out, int out_size, void* d_ws, size_t ws_size,
                              hipStream_t stream) {
    (void)n_in; (void)out_size; (void)ws_size;
    const float* preds = (const float*)d_in[0];
    const float* tgt   = (const float*)d_in[1];
    int N = in_sizes[1] / 6;

    char* ws = (char*)d_ws;
    unsigned* flags    = (unsigned*)(ws + 0);        // FLAGW words = 38400 B
    double*   partials = (double*)(ws + 38400);      // totblk*3 doubles

    int mblk   = (N * 15 + WPB - 1) / WPB;           // 960 for N=256
    int totblk = mblk + OBLK;                        // 1260

    hipMemsetAsync(flags, 0, FLAGW * 4, stream);
    k_work<<<totblk, 256, 0, stream>>>(preds, tgt, N, mblk, flags, partials);
    k_final<<<1, 256, 0, stream>>>(partials, totblk, flags, (float*)d_out);
}

// Round 6
// 18.429 us; speedup vs baseline: 7.2918x; 1.3175x over previous
//
#include <hip/hip_runtime.h>
#include <cmath>

// ---------------- problem constants (idx = 0) ----------------
#define S_    80
#define NBAT  16
#define NA_   3
#define NCH_  255          // NB * (NC + 5)
#define NC_   80
#define PLANE (S_ * S_)    // 6400
#define CELLS (NBAT * NA_ * PLANE)   // 307200
#define MAXENT (256 * 15)  // N * 5 offsets * 3 anchors upper bound
#define WPB   4            // waves per block (masked kernel)
#define MBLK  (MAXENT / WPB)         // 960 masked blocks
#define OB    75                     // obj blocks: 75*256*4 float4 = CELLS/4
#define FLAGW (CELLS / 32)           // 9600 words = 38400 B (fits in LDS)

__device__ __forceinline__ float sp(float x) {   // softplus, stable
    return fmaxf(x, 0.f) + log1pf(__expf(-fabsf(x)));
}

__device__ __forceinline__ float ciou_f(float x1, float y1, float w1, float h1,
                                        float x2, float y2, float w2, float h2) {
    const float EPS = 1e-7f;
    float b1x1 = x1 - w1 * 0.5f, b1x2 = x1 + w1 * 0.5f;
    float b1y1 = y1 - h1 * 0.5f, b1y2 = y1 + h1 * 0.5f;
    float b2x1 = x2 - w2 * 0.5f, b2x2 = x2 + w2 * 0.5f;
    float b2y1 = y2 - h2 * 0.5f, b2y2 = y2 + h2 * 0.5f;
    float iw = fmaxf(fminf(b1x2, b2x2) - fmaxf(b1x1, b2x1), 0.f);
    float ih = fmaxf(fminf(b1y2, b2y2) - fmaxf(b1y1, b2y1), 0.f);
    float inter = iw * ih;
    float uni = w1 * h1 + w2 * h2 - inter + EPS;
    float iou = inter / uni;
    float cw = fmaxf(b1x2, b2x2) - fminf(b1x1, b2x1);
    float ch = fmaxf(b1y2, b2y2) - fminf(b1y1, b2y1);
    float c2 = cw * cw + ch * ch + EPS;
    float dx = b2x1 + b2x2 - b1x1 - b1x2;
    float dy = b2y1 + b2y2 - b1y1 - b1y2;
    float rho2 = (dx * dx + dy * dy) * 0.25f;
    float da = atanf(w2 / (h2 + EPS)) - atanf(w1 / (h1 + EPS));
    float v = 0.40528473456935109f * da * da;   // 4/pi^2
    float alpha = v / (v - iou + (1.f + EPS));
    return iou - (rho2 / c2 + v * alpha);
}

// ---- node 1: block 0 = LDS-bitmap dedup build (no global memset needed);
//              blocks 1..OB = dense softplus(pobj) partial sums (independent).
__global__ void __launch_bounds__(256)
k_build_obj(const float* __restrict__ preds,
            const float* __restrict__ tgt, int N,
            int* __restrict__ count,
            int* __restrict__ lcellcls,     // cell | (cls<<20)
            float4* __restrict__ lbox,
            double* __restrict__ obj_part) {
    if (blockIdx.x == 0) {
        // ---------- build: whole dedup bitmap lives in LDS ----------
        __shared__ unsigned sbm[FLAGW];     // 38400 B
        __shared__ int scount;
        int tid = threadIdx.x;
        for (int i = tid; i < FLAGW; i += 256) sbm[i] = 0u;
        if (tid == 0) scount = 0;
        __syncthreads();

        int n = tid;
        if (n < N) {
            int b   = (int)tgt[n * 6 + 0];
            int cls = (int)tgt[n * 6 + 1];
            float bx = tgt[n * 6 + 2], by = tgt[n * 6 + 3];
            float bw = tgt[n * 6 + 4], bh = tgt[n * 6 + 5];
            if (b >= 0 && b < NBAT) {
                const float ax[3] = {12.f / 8.f, 19.f / 8.f, 40.f / 8.f};
                const float ay[3] = {16.f / 8.f, 36.f / 8.f, 28.f / 8.f};
                bool rm[3];
#pragma unroll
                for (int a = 0; a < 3; ++a) {
                    float rx = bw * S_ / ax[a]; rx = fmaxf(rx, 1.f / rx);
                    float ry = bh * S_ / ay[a]; ry = fmaxf(ry, 1.f / ry);
                    rm[a] = fmaxf(rx, ry) < 4.0f;
                }
                float gx = bx * S_, gy = by * S_;
                int ib = (int)floorf(gx), jb = (int)floorf(gy);
                float oi = gx - floorf(gx), oj = gy - floorf(gy);
                bool pos[5];
                pos[0] = true;
                pos[1] = (oi < 0.5f) && (gx > 1.f);
                pos[2] = (oj < 0.5f) && (gy > 1.f);
                pos[3] = (oi > 0.5f) && ((S_ - gx) > 1.f);
                pos[4] = (oj > 0.5f) && ((S_ - gy) > 1.f);
                const int di[5] = {0, -1, 0, 1, 0};
                const int dj[5] = {0, 0, -1, 0, 1};
#pragma unroll
                for (int k = 0; k < 5; ++k) {
                    if (!pos[k]) continue;
                    int ii = ib + di[k], jj = jb + dj[k];
                    if (ii < 0 || ii >= S_ || jj < 0 || jj >= S_) continue; // ref drops OOB
#pragma unroll
                    for (int a = 0; a < 3; ++a) {
                        if (!rm[a]) continue;
                        int cell = ((b * NA_ + a) * S_ + jj) * S_ + ii;
                        unsigned m = 1u << (cell & 31);
                        unsigned old = atomicOr(&sbm[cell >> 5], m);  // LDS atomic
                        if (!(old & m)) {
                            int e = atomicAdd(&scount, 1);            // LDS atomic
                            lcellcls[e] = cell | (cls << 20);
                            lbox[e] = make_float4(bx, by, bw, bh);
                        }
                    }
                }
            }
        }
        __syncthreads();
        if (tid == 0) *count = scount;
    } else {
        // ---------- dense softplus(pobj): grid-stride x4 float4 ----------
        int base = (blockIdx.x - 1) * 256 + threadIdx.x;   // 19200 threads
        const float4* p4 = (const float4*)preds;
        float v = 0.f;
#pragma unroll
        for (int r = 0; r < 4; ++r) {
            int tid4 = base + r * (OB * 256);              // covers CELLS/4 exactly
            int plane = tid4 / (PLANE / 4);                // 0..47 (= b*3 + a)
            int pos   = tid4 % (PLANE / 4);
            int a = plane % NA_, b = plane / NA_;
            float4 q = p4[(size_t)(b * NCH_ + a * 85 + 4) * (PLANE / 4) + pos];
            v += sp(q.x) + sp(q.y) + sp(q.z) + sp(q.w);
        }
#pragma unroll
        for (int o = 32; o > 0; o >>= 1) v += __shfl_xor(v, o, 64);
        __shared__ float wsum[4];
        int lane = threadIdx.x & 63, wid = threadIdx.x >> 6;
        if (lane == 0) wsum[wid] = v;
        __syncthreads();
        if (threadIdx.x == 0)
            obj_part[blockIdx.x - 1] = (double)(wsum[0] + wsum[1] + wsum[2] + wsum[3]);
    }
}

// ---- node 2: one WAVE per masked cell (list-based gather) ----
__global__ void __launch_bounds__(256)
k_masked(const float* __restrict__ preds,
         const int* __restrict__ count,
         const int* __restrict__ lcellcls,
         const float4* __restrict__ lbox,
         double* __restrict__ partials) {
    int wid = threadIdx.x >> 6, lane = threadIdx.x & 63;
    int t = blockIdx.x * WPB + wid;
    double obj_c = 0.0, box_t = 0.0, cls_s = 0.0;
    if (t < *count) {
        int packed = lcellcls[t];
        int cell = packed & 0xFFFFF;
        int cls  = packed >> 20;
        int x = cell % S_;
        int y = (cell / S_) % S_;
        int a = (cell / PLANE) % NA_;
        int b = cell / (PLANE * NA_);
        const float* base = preds + (size_t)(b * NCH_ + a * 85) * PLANE + y * S_ + x;
        float v0 = base[lane * PLANE];
        float v1 = (lane < 21) ? base[(64 + lane) * PLANE] : 0.f;
        int clsch = 5 + cls;
        float cs = 0.f;
        if (lane >= 5) { cs += sp(v0); if (lane == clsch) cs -= v0; }
        if (lane < 21) { cs += sp(v1); if (64 + lane == clsch) cs -= v1; }
#pragma unroll
        for (int o = 32; o > 0; o >>= 1) cs += __shfl_xor(cs, o, 64);
        float p0 = __shfl(v0, 0, 64);
        float p1 = __shfl(v0, 1, 64);
        float p2 = __shfl(v0, 2, 64);
        float p3 = __shfl(v0, 3, 64);
        float po = __shfl(v0, 4, 64);

        const float anx[3]  = {12.f, 19.f, 40.f};
        const float any_[3] = {16.f, 36.f, 28.f};
        float sx = 1.f / (1.f + __expf(-p0));
        float sy = 1.f / (1.f + __expf(-p1));
        float px = (sx * 2.f - 0.5f + (float)x) * (1.0f / S_);
        float py = (sy * 2.f - 0.5f + (float)y) * (1.0f / S_);
        float pw = __expf(p2) * anx[a] * (1.0f / 640.f);
        float ph = __expf(p3) * any_[a] * (1.0f / 640.f);

        float4 tb = lbox[t];
        float iou = ciou_f(px, py, pw, ph, tb.x, tb.y, tb.z, tb.w);
        if (lane == 0) {
            box_t = (double)(1.f - iou);
            cls_s = (double)cs;
            obj_c = (double)(-fmaxf(iou, 0.f) * po);   // bce(x,t) = sp(x) - t*x
        }
    }
    __shared__ double sm[WPB][3];
    if (lane == 0) { sm[wid][0] = obj_c; sm[wid][1] = box_t; sm[wid][2] = cls_s; }
    __syncthreads();
    if (threadIdx.x == 0) {
        double o = 0, bx = 0, cl = 0;
#pragma unroll
        for (int w = 0; w < WPB; ++w) { o += sm[w][0]; bx += sm[w][1]; cl += sm[w][2]; }
        double* p = partials + (size_t)blockIdx.x * 3;
        p[0] = o; p[1] = bx; p[2] = cl;
    }
}

// ---- node 3: deterministic final reduce + scalar ----
__global__ void k_final(const double* __restrict__ partials,
                        const double* __restrict__ obj_part,
                        const int* __restrict__ count,
                        float* __restrict__ out) {
    __shared__ double so[256], sb[256], sc[256];
    int tid = threadIdx.x;
    double o = 0, b = 0, c = 0;
    for (int i = tid; i < MBLK; i += 256) {
        o += partials[(size_t)i * 3];
        b += partials[(size_t)i * 3 + 1];
        c += partials[(size_t)i * 3 + 2];
    }
    for (int i = tid; i < OB; i += 256) o += obj_part[i];
    so[tid] = o; sb[tid] = b; sc[tid] = c;
    __syncthreads();
    for (int s = 128; s > 0; s >>= 1) {
        if (tid < s) { so[tid] += so[tid + s]; sb[tid] += sb[tid + s]; sc[tid] += sc[tid + s]; }
        __syncthreads();
    }
    if (tid == 0) {
        double nobj  = (double)(*count);
        double denom = fmax(nobj, 1.0);
        double loss_obj = so[0] / (double)CELLS;
        double loss_box = sb[0] / denom;
        double loss_cls = sc[0] / (denom * (double)NC_);
        double loss = (0.7 * 4.0) * loss_obj + 0.3 * loss_cls + 0.05 * loss_box;
        out[0] = (float)(loss * (double)NBAT);
    }
}

extern "C" void kernel_launch(void* const* d_in, const int* in_sizes, int n_in,
                              void* d_out, int out_size, void* d_ws, size_t ws_size,
                              hipStream_t stream) {
    (void)n_in; (void)out_size; (void)ws_size;
    const float* preds = (const float*)d_in[0];
    const float* tgt   = (const float*)d_in[1];
    int N = in_sizes[1] / 6;

    char* ws = (char*)d_ws;
    int*    count    = (int*)(ws + 0);
    int*    lcellcls = (int*)(ws + 64);                     // MAXENT ints
    float4* lbox     = (float4*)(ws + 64 + MAXENT * 4);     // 16B aligned (15424? -> pad)
    // fix alignment: 64 + 15360 = 15424, 15424 % 16 == 0  -> OK
    double* partials = (double*)(ws + 64 + MAXENT * 4 + MAXENT * 16);  // MBLK*3 doubles
    double* obj_part = partials + (size_t)MBLK * 3;                    // OB doubles

    k_build_obj<<<1 + OB, 256, 0, stream>>>(preds, tgt, N, count, lcellcls, lbox, obj_part);
    k_masked<<<MBLK, 256, 0, stream>>>(preds, count, lcellcls, lbox, partials);
    k_final<<<1, 256, 0, stream>>>(partials, obj_part, count, (float*)d_out);
}